// Round 2
// baseline (400.409 us; speedup 1.0000x reference)
//
#include <hip/hip_runtime.h>

// ---------------------------------------------------------------------------
// Qwen3-style attention block on MI355X (gfx950), bf16 MFMA pipeline.
// B=2, S=1024, HID=4096, H=32, KV=8, D=128.
// Stages: cvt(f32->bf16) -> QKV GEMM -> RMSNorm+RoPE -> flash attn -> out GEMM
// GEMMs: 8-phase counted-vmcnt template (BM=128,BN=256,BK=64, triple-buffer,
// lead-2 prefetch, XOR-swizzled LDS, setprio around MFMA clusters).
// ---------------------------------------------------------------------------

typedef __attribute__((ext_vector_type(8))) short s8v;            // 8 bf16 (4 VGPR)
typedef __attribute__((ext_vector_type(4))) float f4v;
typedef __attribute__((ext_vector_type(8))) unsigned short u8v;
typedef __attribute__((ext_vector_type(4))) float float4v;

#define SB() __builtin_amdgcn_sched_barrier(0)

__device__ __forceinline__ unsigned short f2b(float f) {
  unsigned u = __builtin_bit_cast(unsigned, f);
  u += 0x7fffu + ((u >> 16) & 1u);            // round-to-nearest-even
  return (unsigned short)(u >> 16);
}
__device__ __forceinline__ float b2f(unsigned short h) {
  return __builtin_bit_cast(float, (unsigned)h << 16);
}

__device__ __forceinline__ void gload16(const void* g, void* l) {
  __builtin_amdgcn_global_load_lds(
      (const __attribute__((address_space(1))) unsigned int*)g,
      (__attribute__((address_space(3))) unsigned int*)l, 16, 0, 0);
}

// ---------------------------------------------------------------------------
// f32 -> bf16 (vectorized 8/thread)
// ---------------------------------------------------------------------------
__global__ __launch_bounds__(256) void cvt_bf16_k(const float* __restrict__ s,
                                                  unsigned short* __restrict__ d,
                                                  long n) {
  long i = ((long)blockIdx.x * 256 + threadIdx.x) * 8;
  if (i >= n) return;
  float4v a = *(const float4v*)(s + i);
  float4v b = *(const float4v*)(s + i + 4);
  u8v o;
  o[0] = f2b(a[0]); o[1] = f2b(a[1]); o[2] = f2b(a[2]); o[3] = f2b(a[3]);
  o[4] = f2b(b[0]); o[5] = f2b(b[1]); o[6] = f2b(b[2]); o[7] = f2b(b[3]);
  *(u8v*)(d + i) = o;
}

// ---------------------------------------------------------------------------
// 8-phase bf16 GEMM:  C[M,N] = A[M,K] * W[N,K]^T  (K-contiguous rows)
// BM=128, BN=256, BK=64. 512 threads = 8 waves (2M x 4N), 64x64 out per wave.
// LDS: A[3][128*64], B[3][256*64] (144 KiB, triple-buffered, lead-2 staging).
// Swizzle: 16B chunk index ^= (row & 7); linear gload_lds dest +
// inverse-swizzled global source + swizzled ds_read (rule 21).
// Main-loop wait is vmcnt(6): tile kt+2's 6 loads stay in flight (T4).
// ---------------------------------------------------------------------------
template <bool F32OUT>
__global__ __launch_bounds__(512, 2) void gemm8p(const unsigned short* __restrict__ A,
                                                 const unsigned short* __restrict__ W,
                                                 void* __restrict__ Cv,
                                                 int K, int ldc) {
  __shared__ __align__(16) unsigned short Ab[3][128 * 64];
  __shared__ __align__(16) unsigned short Bb[3][256 * 64];
  const int tid = threadIdx.x;
  const int lane = tid & 63;
  const int w = tid >> 6;
  const int wr = w >> 2, wc = w & 3;
  const int lr = lane & 15, lg = lane >> 4;
  const long m0 = (long)blockIdx.y * 128, n0 = (long)blockIdx.x * 256;

  // ---- staging geometry: thread covers physical 16B chunk id = l*512+tid ----
  const int srow = tid >> 3;                       // row within 64-row stripe
  const int sc = (tid & 7) ^ (srow & 7);           // inverse-swizzled src chunk

  auto stA = [&](int b, int kt) {                  // 2 loads (rows srow, srow+64)
    const unsigned short* s = A + (m0 + srow) * K + (long)kt * 64 + sc * 8;
#pragma unroll
    for (int l = 0; l < 2; ++l)
      gload16(s + (long)l * 64 * K, &Ab[b][(l * 512 + tid) * 8]);
  };
  auto stB2 = [&](int b, int kt, int l0) {         // 2 loads (rows +l0*64, +(l0+1)*64)
    const unsigned short* s = W + (n0 + srow) * K + (long)kt * 64 + sc * 8;
#pragma unroll
    for (int l = 0; l < 2; ++l)
      gload16(s + (long)(l0 + l) * 64 * K, &Bb[b][((l0 + l) * 512 + tid) * 8]);
  };

  // ---- fragment read addressing (swizzled) ----
  const int sw0 = (lg ^ (lr & 7)) << 3;            // ks=0 chunk lg
  const int sw1 = ((4 + lg) ^ (lr & 7)) << 3;      // ks=1 chunk 4+lg
  const int abase = wr * 64 + lr;
  const int bbase = wc * 64 + lr;

  f4v acc[4][4];
#pragma unroll
  for (int i = 0; i < 4; ++i)
#pragma unroll
    for (int j = 0; j < 4; ++j) acc[i][j] = (f4v){0.f, 0.f, 0.f, 0.f};

  const int nk = K >> 6;

  // ---- prologue: stage tiles 0 and 1; wait for tile 0 only ----
  stA(0, 0); stB2(0, 0, 0); stB2(0, 0, 2);
  stA(1, 1); stB2(1, 1, 0); stB2(1, 1, 2);
  asm volatile("s_waitcnt vmcnt(6)" ::: "memory");
  SB();
  __builtin_amdgcn_s_barrier();
  SB();

  int cur = 0, st = 2;
  for (int kt = 0; kt < nk; ++kt) {
    const unsigned short* Ap = Ab[cur];
    const unsigned short* Bp = Bb[cur];
    const bool more = (kt + 2 < nk);

    // ================= phase 0: row-frags 0,1 x all cols =================
    s8v a0[2][2], bfr[4][2];
#pragma unroll
    for (int i = 0; i < 2; ++i) {
      a0[i][0] = *(const s8v*)&Ap[(abase + i * 16) * 64 + sw0];
      a0[i][1] = *(const s8v*)&Ap[(abase + i * 16) * 64 + sw1];
    }
#pragma unroll
    for (int j = 0; j < 4; ++j) {
      bfr[j][0] = *(const s8v*)&Bp[(bbase + j * 16) * 64 + sw0];
      bfr[j][1] = *(const s8v*)&Bp[(bbase + j * 16) * 64 + sw1];
    }
    if (more) { stA(st, kt + 2); stB2(st, kt + 2, 0); }
    SB();
    __builtin_amdgcn_s_barrier();
    SB();
    __builtin_amdgcn_s_setprio(1);
#pragma unroll
    for (int i = 0; i < 2; ++i)
#pragma unroll
      for (int j = 0; j < 4; ++j) {
        acc[i][j] = __builtin_amdgcn_mfma_f32_16x16x32_bf16(a0[i][0], bfr[j][0], acc[i][j], 0, 0, 0);
        acc[i][j] = __builtin_amdgcn_mfma_f32_16x16x32_bf16(a0[i][1], bfr[j][1], acc[i][j], 0, 0, 0);
      }
    __builtin_amdgcn_s_setprio(0);
    SB();
    __builtin_amdgcn_s_barrier();
    SB();

    // ================= phase 1: row-frags 2,3 x all cols =================
    s8v a1[2][2];
#pragma unroll
    for (int i = 0; i < 2; ++i) {
      a1[i][0] = *(const s8v*)&Ap[(abase + (i + 2) * 16) * 64 + sw0];
      a1[i][1] = *(const s8v*)&Ap[(abase + (i + 2) * 16) * 64 + sw1];
    }
    if (more) stB2(st, kt + 2, 2);
    SB();
    __builtin_amdgcn_s_barrier();
    SB();
    __builtin_amdgcn_s_setprio(1);
#pragma unroll
    for (int i = 0; i < 2; ++i)
#pragma unroll
      for (int j = 0; j < 4; ++j) {
        acc[i + 2][j] = __builtin_amdgcn_mfma_f32_16x16x32_bf16(a1[i][0], bfr[j][0], acc[i + 2][j], 0, 0, 0);
        acc[i + 2][j] = __builtin_amdgcn_mfma_f32_16x16x32_bf16(a1[i][1], bfr[j][1], acc[i + 2][j], 0, 0, 0);
      }
    __builtin_amdgcn_s_setprio(0);
    // counted wait: tile kt+1 (6 oldest) must be landed; keep tile kt+2 in flight
    if (more) asm volatile("s_waitcnt vmcnt(6)" ::: "memory");
    else      asm volatile("s_waitcnt vmcnt(0)" ::: "memory");
    SB();
    __builtin_amdgcn_s_barrier();
    SB();

    cur = (cur == 2) ? 0 : cur + 1;
    st = (st == 2) ? 0 : st + 1;
  }

  // ---- epilogue ----
  if constexpr (F32OUT) {
    float* C = (float*)Cv;
#pragma unroll
    for (int i = 0; i < 4; ++i) {
      long row = m0 + wr * 64 + i * 16 + lg * 4;
#pragma unroll
      for (int j = 0; j < 4; ++j) {
        long col = n0 + wc * 64 + j * 16 + lr;
#pragma unroll
        for (int r = 0; r < 4; ++r) C[(row + r) * ldc + col] = acc[i][j][r];
      }
    }
  } else {
    unsigned short* C = (unsigned short*)Cv;
#pragma unroll
    for (int i = 0; i < 4; ++i) {
      long row = m0 + wr * 64 + i * 16 + lg * 4;
#pragma unroll
      for (int j = 0; j < 4; ++j) {
        long col = n0 + wc * 64 + j * 16 + lr;
#pragma unroll
        for (int r = 0; r < 4; ++r) C[(row + r) * ldc + col] = f2b(acc[i][j][r]);
      }
    }
  }
}

// ---------------------------------------------------------------------------
// Per-head RMSNorm (D=128) + RoPE, in-place on the bf16 qkv buffer.
// ---------------------------------------------------------------------------
__global__ __launch_bounds__(256) void rms_rope_k(unsigned short* __restrict__ qkv,
                                                  const float* __restrict__ fc,
                                                  const float* __restrict__ qw,
                                                  const float* __restrict__ kw) {
  int idx = blockIdx.x * 4 + (threadIdx.x >> 6);
  int lane = threadIdx.x & 63;
  int head = idx % 40;                 // 0..31 = Q heads, 32..39 = K heads
  int row = idx / 40;                  // b*1024 + s
  int s = row & 1023;
  unsigned short* p;
  const float* w;
  if (head < 32) { p = qkv + (long)row * 6144 + head * 128; w = qw; }
  else           { p = qkv + (long)row * 6144 + 4096 + (head - 32) * 128; w = kw; }
  float x0 = b2f(p[lane]), x1 = b2f(p[lane + 64]);
  float ss = x0 * x0 + x1 * x1;
#pragma unroll
  for (int off = 32; off; off >>= 1) ss += __shfl_xor(ss, off);
  float r = rsqrtf(ss * (1.0f / 128.0f) + 1e-6f);
  float y0 = x0 * r * w[lane], y1 = x1 * r * w[lane + 64];
  const float* cosp = fc + (long)s * 128;
  const float* sinp = cosp + 1024 * 128;
  const float* nsinp = sinp + 1024 * 128;
  float e0 = y0 * cosp[lane] + y1 * nsinp[lane];
  float e1 = y1 * cosp[lane + 64] + y0 * sinp[lane + 64];
  p[lane] = f2b(e0);
  p[lane + 64] = f2b(e1);
}

// ---------------------------------------------------------------------------
// Flash attention (no mask), GQA 4:1. Block = 4 waves = 64 q-rows; 64-key tiles.
// ---------------------------------------------------------------------------
__global__ __launch_bounds__(256) void attn_k(const unsigned short* __restrict__ qkv,
                                              unsigned short* __restrict__ ao) {
  __shared__ unsigned short Kt[64 * 128];   // [key][d], rows 256B, XOR-swizzled
  __shared__ unsigned short Vt[128 * 72];   // [d][key], padded rows (144B)
  __shared__ unsigned short Pl[4 * 1024];   // per-wave 16x64 P, XOR-swizzled

  const int bid = blockIdx.x;
  const int qt = bid & 15;
  const int h = (bid >> 4) & 31;
  const int b = bid >> 9;
  const int kvh = h >> 2;
  const int tid = threadIdx.x, lane = tid & 63, w = tid >> 6;
  const int lr = lane & 15, lg = lane >> 4;

  const unsigned short* Qb =
      qkv + (long)(b * 1024 + qt * 64 + w * 16 + lr) * 6144 + h * 128;
  s8v qf[4];
#pragma unroll
  for (int ks = 0; ks < 4; ++ks) qf[ks] = *(const s8v*)(Qb + ks * 32 + lg * 8);

  f4v o[8];
#pragma unroll
  for (int n = 0; n < 8; ++n) o[n] = (f4v){0.f, 0.f, 0.f, 0.f};
  float m[4], l[4];
#pragma unroll
  for (int r = 0; r < 4; ++r) { m[r] = -1e30f; l[r] = 0.f; }

  const float SL = 0.08838834764831845f * 1.4426950408889634f;  // D^-1/2 * log2(e)
  const long krow = (long)b * 1024 * 6144 + 4096 + kvh * 128;
  const long vrow = (long)b * 1024 * 6144 + 5120 + kvh * 128;

  for (int kt = 0; kt < 16; ++kt) {
    __syncthreads();
#pragma unroll
    for (int t = 0; t < 4; ++t) {
      int c = t * 256 + tid;
      int row = c >> 4;
      int sc = (c & 15) ^ (row & 7);
      gload16(qkv + krow + (long)(kt * 64 + row) * 6144 + sc * 8, &Kt[c * 8]);
    }
#pragma unroll
    for (int t = 0; t < 4; ++t) {
      int c = t * 256 + tid;
      int key = c & 63;
      int d0 = (c >> 6) * 8;
      s8v v = *(const s8v*)(qkv + vrow + (long)(kt * 64 + key) * 6144 + d0);
#pragma unroll
      for (int i = 0; i < 8; ++i) Vt[(d0 + i) * 72 + key] = (unsigned short)v[i];
    }
    __syncthreads();

    f4v sacc[4];
#pragma unroll
    for (int j = 0; j < 4; ++j) sacc[j] = (f4v){0.f, 0.f, 0.f, 0.f};
#pragma unroll
    for (int ks = 0; ks < 4; ++ks) {
#pragma unroll
      for (int j = 0; j < 4; ++j) {
        int key = j * 16 + lr;
        s8v kf = *(const s8v*)&Kt[key * 128 + (((ks * 64 + lg * 16) ^ ((key & 7) << 4)) >> 1)];
        sacc[j] = __builtin_amdgcn_mfma_f32_16x16x32_bf16(qf[ks], kf, sacc[j], 0, 0, 0);
      }
    }

    float sm[4];
#pragma unroll
    for (int r = 0; r < 4; ++r)
      sm[r] = fmaxf(fmaxf(sacc[0][r], sacc[1][r]), fmaxf(sacc[2][r], sacc[3][r]));
#pragma unroll
    for (int off = 1; off < 16; off <<= 1)
#pragma unroll
      for (int r = 0; r < 4; ++r) sm[r] = fmaxf(sm[r], __shfl_xor(sm[r], off));
    float alpha[4];
#pragma unroll
    for (int r = 0; r < 4; ++r) {
      float nm = fmaxf(m[r], sm[r] * SL);
      alpha[r] = exp2f(m[r] - nm);
      m[r] = nm;
      l[r] *= alpha[r];
    }
#pragma unroll
    for (int n = 0; n < 8; ++n)
#pragma unroll
      for (int r = 0; r < 4; ++r) o[n][r] *= alpha[r];

    unsigned short* pw = Pl + w * 1024;
#pragma unroll
    for (int j = 0; j < 4; ++j)
#pragma unroll
      for (int r = 0; r < 4; ++r) {
        float p = exp2f(sacc[j][r] * SL - m[r]);
        l[r] += p;
        int prow = lg * 4 + r, pcol = j * 16 + lr;
        pw[(prow * 128 + ((pcol * 2) ^ ((prow & 7) << 4))) >> 1] = f2b(p);
      }

#pragma unroll
    for (int ks = 0; ks < 2; ++ks) {
      int bo = ks * 64 + lg * 16;
      s8v pf = *(const s8v*)&Pl[w * 1024 + ((lr * 128 + (bo ^ ((lr & 7) << 4))) >> 1)];
#pragma unroll
      for (int n = 0; n < 8; ++n) {
        s8v vf = *(const s8v*)&Vt[(n * 16 + lr) * 72 + ks * 32 + lg * 8];
        o[n] = __builtin_amdgcn_mfma_f32_16x16x32_bf16(pf, vf, o[n], 0, 0, 0);
      }
    }
  }

#pragma unroll
  for (int off = 1; off < 16; off <<= 1)
#pragma unroll
    for (int r = 0; r < 4; ++r) l[r] += __shfl_xor(l[r], off);
  float inv[4];
#pragma unroll
  for (int r = 0; r < 4; ++r) inv[r] = 1.f / l[r];
  const long ob = (long)(b * 1024 + qt * 64 + w * 16) * 4096 + h * 128;
#pragma unroll
  for (int n = 0; n < 8; ++n)
#pragma unroll
    for (int r = 0; r < 4; ++r)
      ao[ob + (long)(lg * 4 + r) * 4096 + n * 16 + lr] = f2b(o[n][r] * inv[r]);
}

// ---------------------------------------------------------------------------
// Launch
// ---------------------------------------------------------------------------
extern "C" void kernel_launch(void* const* d_in, const int* in_sizes, int n_in,
                              void* d_out, int out_size, void* d_ws, size_t ws_size,
                              hipStream_t stream) {
  const float* hidden = (const float*)d_in[0];
  const float* fc     = (const float*)d_in[1];
  const float* Wq     = (const float*)d_in[2];
  const float* Wk     = (const float*)d_in[3];
  const float* Wv     = (const float*)d_in[4];
  const float* Wo     = (const float*)d_in[5];
  const float* qw     = (const float*)d_in[6];
  const float* kw     = (const float*)d_in[7];

  unsigned short* hb  = (unsigned short*)d_ws;                 // [2048][4096]
  unsigned short* wb  = hb + (long)2048 * 4096;                // [10240][4096] (Wq|Wk|Wv|Wo)
  unsigned short* qkv = wb + (long)10240 * 4096;               // [2048][6144]
  unsigned short* ao  = qkv + (long)2048 * 6144;               // [2048][4096]

  cvt_bf16_k<<<4096, 256, 0, stream>>>(hidden, hb, (long)8388608);
  cvt_bf16_k<<<8192, 256, 0, stream>>>(Wq, wb, (long)16777216);
  cvt_bf16_k<<<2048, 256, 0, stream>>>(Wk, wb + (long)4096 * 4096, (long)4194304);
  cvt_bf16_k<<<2048, 256, 0, stream>>>(Wv, wb + (long)5120 * 4096, (long)4194304);
  cvt_bf16_k<<<8192, 256, 0, stream>>>(Wo, wb + (long)6144 * 4096, (long)16777216);

  // fused QKV projection: [2048,4096] x [6144,4096]^T -> bf16 [2048,6144]
  gemm8p<false><<<dim3(24, 16), 512, 0, stream>>>(hb, wb, qkv, 4096, 6144);

  // per-head RMSNorm + RoPE in place
  rms_rope_k<<<20480, 256, 0, stream>>>(qkv, fc, qw, kw);

  // flash attention -> bf16 [2048][4096]
  attn_k<<<1024, 256, 0, stream>>>(qkv, ao);

  // output projection -> f32 d_out
  gemm8p<true><<<dim3(16, 16), 512, 0, stream>>>(ao, wb + (long)6144 * 4096, d_out,
                                                 4096, 4096);
}

// Round 3
// 397.581 us; speedup vs baseline: 1.0071x; 1.0071x over previous
//
#include <hip/hip_runtime.h>

// ---------------------------------------------------------------------------
// Qwen3-style attention block on MI355X (gfx950), bf16 MFMA pipeline.
// B=2, S=1024, HID=4096, H=32, KV=8, D=128.
// Stages: cvt(f32->bf16, fused) -> QKV GEMM -> RMSNorm+RoPE -> flash attn
//         -> out GEMM.
// GEMM: faithful m201 8-phase template. BM=BN=256, BK=64, 8 waves (2Mx4N),
// one half-tile staged per phase into the just-freed slot, quadrant MFMA
// clusters (16/phase), counted vmcnt(6) once per K-tile, setprio + SB pins,
// conflict-free chunk-XOR LDS swizzle (both-sides: pre-swizzled global src).
// ---------------------------------------------------------------------------

typedef __attribute__((ext_vector_type(8))) short s8v;            // 8 bf16 (4 VGPR)
typedef __attribute__((ext_vector_type(4))) float f4v;
typedef __attribute__((ext_vector_type(8))) unsigned short u8v;
typedef __attribute__((ext_vector_type(4))) float float4v;
typedef unsigned short us;

#define SB() __builtin_amdgcn_sched_barrier(0)

__device__ __forceinline__ void BARRIER() {
  asm volatile("" ::: "memory");
  __builtin_amdgcn_s_barrier();
  asm volatile("" ::: "memory");
}

__device__ __forceinline__ us f2b(float f) {
  unsigned u = __builtin_bit_cast(unsigned, f);
  u += 0x7fffu + ((u >> 16) & 1u);            // round-to-nearest-even
  return (us)(u >> 16);
}
__device__ __forceinline__ float b2f(us h) {
  return __builtin_bit_cast(float, (unsigned)h << 16);
}

__device__ __forceinline__ void gload16(const void* g, void* l) {
  __builtin_amdgcn_global_load_lds(
      (const __attribute__((address_space(1))) unsigned int*)g,
      (__attribute__((address_space(3))) unsigned int*)l, 16, 0, 0);
}

// ---------------------------------------------------------------------------
// Fused f32 -> bf16 convert: all 5 tensors, contiguous bf16 destination.
// Block = 2048 elements. Ranges (blocks): hidden 4096 | Wq 8192 | Wk 2048 |
// Wv 2048 | Wo 8192  => 24576 blocks total.
// ---------------------------------------------------------------------------
__global__ __launch_bounds__(256) void cvt_all_k(const float* __restrict__ h,
                                                 const float* __restrict__ wq,
                                                 const float* __restrict__ wk,
                                                 const float* __restrict__ wv,
                                                 const float* __restrict__ wo,
                                                 us* __restrict__ dst) {
  long blk = blockIdx.x;
  const float* src;
  long off;
  if (blk < 4096)        { src = h;  off = 0; }
  else if (blk < 12288)  { src = wq; off = 4096; }
  else if (blk < 14336)  { src = wk; off = 12288; }
  else if (blk < 16384)  { src = wv; off = 14336; }
  else                   { src = wo; off = 16384; }
  long i = (blk - off) * 2048 + (long)threadIdx.x * 8;
  long o = blk * 2048 + (long)threadIdx.x * 8;
  float4v a = *(const float4v*)(src + i);
  float4v b = *(const float4v*)(src + i + 4);
  u8v v;
  v[0] = f2b(a[0]); v[1] = f2b(a[1]); v[2] = f2b(a[2]); v[3] = f2b(a[3]);
  v[4] = f2b(b[0]); v[5] = f2b(b[1]); v[6] = f2b(b[2]); v[7] = f2b(b[3]);
  *(u8v*)(dst + o) = v;
}

// ---------------------------------------------------------------------------
// m201-style 8-phase bf16 GEMM: C[M,N] = A[M,K] * W[N,K]^T
// 256x256 tile, BK=64, 512 threads (8 waves, 2M x 4N).
// LDS: [2 dbuf][2 half][128x64] for A and B = 128 KiB.
// Wave output: rows {qm*128 + wr*64 + f*16}, cols {qn*128 + wc*32 + g*16}.
// Phases per K-tile: q(0,0) q(0,1) q(1,1) q(1,0); reads 12,4,8,4 ds_read_b128;
// stage 1 half-tile per phase; vmcnt(6) at phase 4 (3 half-tiles in flight).
// ---------------------------------------------------------------------------
template <bool F32OUT>
__global__ __launch_bounds__(512, 2) void gemm8p(const us* __restrict__ A,
                                                 const us* __restrict__ W,
                                                 void* __restrict__ Cv,
                                                 int K, int ldc, int NX) {
  __shared__ __align__(16) us Ah[2][2][128 * 64];
  __shared__ __align__(16) us Bh[2][2][128 * 64];
  const int tid = threadIdx.x, lane = tid & 63, w = tid >> 6;
  const int wr = w >> 2, wc = w & 3;
  const int lr = lane & 15, lg = lane >> 4;

  // XCD-chunked bijective swizzle (gridDim.x divisible by 8: 192 / 128)
  const int cpx = (int)gridDim.x >> 3;
  const int swz = ((int)blockIdx.x & 7) * cpx + ((int)blockIdx.x >> 3);
  const long m0 = (long)(swz / NX) * 256;
  const long n0 = (long)(swz % NX) * 256;

  // staging geometry: thread covers 16B chunks c0, c1 of a 128x64 half-tile
  const int c0 = tid, c1 = 512 + tid;
  const int r0 = c0 >> 3, r1 = c1 >> 3;
  const int s0 = ((c0 & 7) ^ (r0 & 7)) << 3;       // inverse-swizzled src col
  const int s1 = ((c1 & 7) ^ (r1 & 7)) << 3;

#define STG(dst, src)                                                   \
  do {                                                                  \
    const us* _s = (src);                                               \
    us* _d = (dst);                                                     \
    gload16(_s + (long)r0 * K + s0, _d + c0 * 8);                       \
    gload16(_s + (long)r1 * K + s1, _d + c1 * 8);                       \
  } while (0)

  const us* Asrc = A + m0 * K;     // half h at + h*128*K, K-tile kt at + kt*64
  const us* Bsrc = W + n0 * K;
  const long hK = (long)128 * K;

  // fragment read offsets (elements; row*64 + swizzled-chunk*8)
  const int ra = wr * 64 + lr, rb = wc * 32 + lr;
  const int offA0 = ra * 64 + ((lg ^ (ra & 7)) << 3);
  const int offA1 = ra * 64 + (((4 + lg) ^ (ra & 7)) << 3);
  const int offB0 = rb * 64 + ((lg ^ (rb & 7)) << 3);
  const int offB1 = rb * 64 + (((4 + lg) ^ (rb & 7)) << 3);

  f4v acc[8][4];
#pragma unroll
  for (int i = 0; i < 8; ++i)
#pragma unroll
    for (int j = 0; j < 4; ++j) acc[i][j] = (f4v){0.f, 0.f, 0.f, 0.f};

  const int nk = K >> 6;

  // prologue: A0(0) B0(0) B1(0) A1(0) | A0(1) B1(1) A1(1)  (7 half-tiles)
  STG(Ah[0][0], Asrc);
  STG(Bh[0][0], Bsrc);
  STG(Bh[0][1], Bsrc + hK);
  STG(Ah[0][1], Asrc + hK);
  STG(Ah[1][0], Asrc + 64);
  STG(Bh[1][1], Bsrc + hK + 64);
  STG(Ah[1][1], Asrc + hK + 64);
  asm volatile("s_waitcnt vmcnt(6)" ::: "memory");   // tile 0 landed
  BARRIER();

  s8v a[4][2], b[2][2];

#define RD_A(H)                                                         \
  _Pragma("unroll") for (int f = 0; f < 4; ++f) {                       \
    a[f][0] = *(const s8v*)(&Ah[d][H][offA0 + f * 1024]);               \
    a[f][1] = *(const s8v*)(&Ah[d][H][offA1 + f * 1024]);               \
  }
#define RD_B(H)                                                         \
  _Pragma("unroll") for (int g = 0; g < 2; ++g) {                       \
    b[g][0] = *(const s8v*)(&Bh[d][H][offB0 + g * 1024]);               \
    b[g][1] = *(const s8v*)(&Bh[d][H][offB1 + g * 1024]);               \
  }
#define QUAD(QM, QN)                                                    \
  __builtin_amdgcn_s_setprio(1);                                        \
  _Pragma("unroll") for (int f = 0; f < 4; ++f)                         \
  _Pragma("unroll") for (int g = 0; g < 2; ++g) {                       \
    f4v t = acc[QM * 4 + f][QN * 2 + g];                                \
    t = __builtin_amdgcn_mfma_f32_16x16x32_bf16(a[f][0], b[g][0], t, 0, 0, 0); \
    t = __builtin_amdgcn_mfma_f32_16x16x32_bf16(a[f][1], b[g][1], t, 0, 0, 0); \
    acc[QM * 4 + f][QN * 2 + g] = t;                                    \
  }                                                                     \
  __builtin_amdgcn_s_setprio(0);

  for (int kt = 0; kt < nk; ++kt) {
    const int d = kt & 1;
    const long kb2 = (long)(kt + 2) * 64;
    const bool p1 = (kt + 1 < nk), p2 = (kt + 2 < nk);

    // ---- phase 1: q(0,0); stage B0(kt+1) -> other dbuf ----
    RD_A(0)
    RD_B(0)
    if (p1) STG(Bh[d ^ 1][0], Bsrc + (long)(kt + 1) * 64);
    BARRIER(); SB();
    QUAD(0, 0)
    SB(); BARRIER();

    // ---- phase 2: q(0,1); stage A0(kt+2) into freed A0 slot ----
    RD_B(1)
    if (p2) STG(Ah[d][0], Asrc + kb2);
    BARRIER(); SB();
    QUAD(0, 1)
    SB(); BARRIER();

    // ---- phase 3: q(1,1); stage B1(kt+2) into freed B1 slot ----
    RD_A(1)
    if (p2) STG(Bh[d][1], Bsrc + hK + kb2);
    BARRIER(); SB();
    QUAD(1, 1)
    SB(); BARRIER();

    // ---- phase 4: q(1,0); stage A1(kt+2); counted vmcnt once per tile ----
    RD_B(0)
    if (p2) STG(Ah[d][1], Asrc + hK + kb2);
    BARRIER(); SB();
    QUAD(1, 0)
    SB();
    if (p2) asm volatile("s_waitcnt vmcnt(6)" ::: "memory");
    else    asm volatile("s_waitcnt vmcnt(0)" ::: "memory");
    BARRIER();
  }

  // ---- epilogue ----
#pragma unroll
  for (int qm = 0; qm < 2; ++qm)
#pragma unroll
    for (int f = 0; f < 4; ++f) {
      long row = m0 + qm * 128 + wr * 64 + f * 16 + lg * 4;
#pragma unroll
      for (int qn = 0; qn < 2; ++qn)
#pragma unroll
        for (int g = 0; g < 2; ++g) {
          long col = n0 + qn * 128 + wc * 32 + g * 16 + lr;
          f4v v = acc[qm * 4 + f][qn * 2 + g];
          if constexpr (F32OUT) {
            float* C = (float*)Cv;
#pragma unroll
            for (int r = 0; r < 4; ++r) C[(row + r) * ldc + col] = v[r];
          } else {
            us* C = (us*)Cv;
#pragma unroll
            for (int r = 0; r < 4; ++r) C[(row + r) * ldc + col] = f2b(v[r]);
          }
        }
    }
#undef STG
#undef RD_A
#undef RD_B
#undef QUAD
}

// ---------------------------------------------------------------------------
// Per-head RMSNorm (D=128) + RoPE, in-place on the bf16 qkv buffer.
// ---------------------------------------------------------------------------
__global__ __launch_bounds__(256) void rms_rope_k(us* __restrict__ qkv,
                                                  const float* __restrict__ fc,
                                                  const float* __restrict__ qw,
                                                  const float* __restrict__ kw) {
  int idx = blockIdx.x * 4 + (threadIdx.x >> 6);
  int lane = threadIdx.x & 63;
  int head = idx % 40;                 // 0..31 = Q heads, 32..39 = K heads
  int row = idx / 40;                  // b*1024 + s
  int s = row & 1023;
  us* p;
  const float* w;
  if (head < 32) { p = qkv + (long)row * 6144 + head * 128; w = qw; }
  else           { p = qkv + (long)row * 6144 + 4096 + (head - 32) * 128; w = kw; }
  float x0 = b2f(p[lane]), x1 = b2f(p[lane + 64]);
  float ss = x0 * x0 + x1 * x1;
#pragma unroll
  for (int off = 32; off; off >>= 1) ss += __shfl_xor(ss, off);
  float r = rsqrtf(ss * (1.0f / 128.0f) + 1e-6f);
  float y0 = x0 * r * w[lane], y1 = x1 * r * w[lane + 64];
  const float* cosp = fc + (long)s * 128;
  const float* sinp = cosp + 1024 * 128;
  const float* nsinp = sinp + 1024 * 128;
  float e0 = y0 * cosp[lane] + y1 * nsinp[lane];
  float e1 = y1 * cosp[lane + 64] + y0 * sinp[lane + 64];
  p[lane] = f2b(e0);
  p[lane + 64] = f2b(e1);
}

// ---------------------------------------------------------------------------
// Flash attention (no mask), GQA 4:1. Block = 4 waves = 64 q-rows; 64-key tiles.
// ---------------------------------------------------------------------------
__global__ __launch_bounds__(256) void attn_k(const us* __restrict__ qkv,
                                              us* __restrict__ ao) {
  __shared__ us Kt[64 * 128];   // [key][d], rows 256B, XOR-swizzled
  __shared__ us Vt[128 * 72];   // [d][key], padded rows (144B)
  __shared__ us Pl[4 * 1024];   // per-wave 16x64 P, XOR-swizzled

  const int bid = blockIdx.x;
  const int qt = bid & 15;
  const int h = (bid >> 4) & 31;
  const int b = bid >> 9;
  const int kvh = h >> 2;
  const int tid = threadIdx.x, lane = tid & 63, w = tid >> 6;
  const int lr = lane & 15, lg = lane >> 4;

  const us* Qb =
      qkv + (long)(b * 1024 + qt * 64 + w * 16 + lr) * 6144 + h * 128;
  s8v qf[4];
#pragma unroll
  for (int ks = 0; ks < 4; ++ks) qf[ks] = *(const s8v*)(Qb + ks * 32 + lg * 8);

  f4v o[8];
#pragma unroll
  for (int n = 0; n < 8; ++n) o[n] = (f4v){0.f, 0.f, 0.f, 0.f};
  float m[4], l[4];
#pragma unroll
  for (int r = 0; r < 4; ++r) { m[r] = -1e30f; l[r] = 0.f; }

  const float SL = 0.08838834764831845f * 1.4426950408889634f;  // D^-1/2 * log2e
  const long krow = (long)b * 1024 * 6144 + 4096 + kvh * 128;
  const long vrow = (long)b * 1024 * 6144 + 5120 + kvh * 128;

  for (int kt = 0; kt < 16; ++kt) {
    __syncthreads();
#pragma unroll
    for (int t = 0; t < 4; ++t) {
      int c = t * 256 + tid;
      int row = c >> 4;
      int sc = (c & 15) ^ (row & 7);
      gload16(qkv + krow + (long)(kt * 64 + row) * 6144 + sc * 8, &Kt[c * 8]);
    }
#pragma unroll
    for (int t = 0; t < 4; ++t) {
      int c = t * 256 + tid;
      int key = c & 63;
      int d0 = (c >> 6) * 8;
      s8v v = *(const s8v*)(qkv + vrow + (long)(kt * 64 + key) * 6144 + d0);
#pragma unroll
      for (int i = 0; i < 8; ++i) Vt[(d0 + i) * 72 + key] = (us)v[i];
    }
    __syncthreads();

    f4v sacc[4];
#pragma unroll
    for (int j = 0; j < 4; ++j) sacc[j] = (f4v){0.f, 0.f, 0.f, 0.f};
#pragma unroll
    for (int ks = 0; ks < 4; ++ks) {
#pragma unroll
      for (int j = 0; j < 4; ++j) {
        int key = j * 16 + lr;
        s8v kf = *(const s8v*)&Kt[key * 128 + (((ks * 64 + lg * 16) ^ ((key & 7) << 4)) >> 1)];
        sacc[j] = __builtin_amdgcn_mfma_f32_16x16x32_bf16(qf[ks], kf, sacc[j], 0, 0, 0);
      }
    }

    float sm[4];
#pragma unroll
    for (int r = 0; r < 4; ++r)
      sm[r] = fmaxf(fmaxf(sacc[0][r], sacc[1][r]), fmaxf(sacc[2][r], sacc[3][r]));
#pragma unroll
    for (int off = 1; off < 16; off <<= 1)
#pragma unroll
      for (int r = 0; r < 4; ++r) sm[r] = fmaxf(sm[r], __shfl_xor(sm[r], off));
    float alpha[4];
#pragma unroll
    for (int r = 0; r < 4; ++r) {
      float nm = fmaxf(m[r], sm[r] * SL);
      alpha[r] = exp2f(m[r] - nm);
      m[r] = nm;
      l[r] *= alpha[r];
    }
#pragma unroll
    for (int n = 0; n < 8; ++n)
#pragma unroll
      for (int r = 0; r < 4; ++r) o[n][r] *= alpha[r];

    us* pw = Pl + w * 1024;
#pragma unroll
    for (int j = 0; j < 4; ++j)
#pragma unroll
      for (int r = 0; r < 4; ++r) {
        float p = exp2f(sacc[j][r] * SL - m[r]);
        l[r] += p;
        int prow = lg * 4 + r, pcol = j * 16 + lr;
        pw[(prow * 128 + ((pcol * 2) ^ ((prow & 7) << 4))) >> 1] = f2b(p);
      }

#pragma unroll
    for (int ks = 0; ks < 2; ++ks) {
      int bo = ks * 64 + lg * 16;
      s8v pf = *(const s8v*)&Pl[w * 1024 + ((lr * 128 + (bo ^ ((lr & 7) << 4))) >> 1)];
#pragma unroll
      for (int n = 0; n < 8; ++n) {
        s8v vf = *(const s8v*)&Vt[(n * 16 + lr) * 72 + ks * 32 + lg * 8];
        o[n] = __builtin_amdgcn_mfma_f32_16x16x32_bf16(pf, vf, o[n], 0, 0, 0);
      }
    }
  }

#pragma unroll
  for (int off = 1; off < 16; off <<= 1)
#pragma unroll
    for (int r = 0; r < 4; ++r) l[r] += __shfl_xor(l[r], off);
  float inv[4];
#pragma unroll
  for (int r = 0; r < 4; ++r) inv[r] = 1.f / l[r];
  const long ob = (long)(b * 1024 + qt * 64 + w * 16) * 4096 + h * 128;
#pragma unroll
  for (int n = 0; n < 8; ++n)
#pragma unroll
    for (int r = 0; r < 4; ++r)
      ao[ob + (long)(lg * 4 + r) * 4096 + n * 16 + lr] = f2b(o[n][r] * inv[r]);
}

// ---------------------------------------------------------------------------
// Launch
// ---------------------------------------------------------------------------
extern "C" void kernel_launch(void* const* d_in, const int* in_sizes, int n_in,
                              void* d_out, int out_size, void* d_ws, size_t ws_size,
                              hipStream_t stream) {
  const float* hidden = (const float*)d_in[0];
  const float* fc     = (const float*)d_in[1];
  const float* Wq     = (const float*)d_in[2];
  const float* Wk     = (const float*)d_in[3];
  const float* Wv     = (const float*)d_in[4];
  const float* Wo     = (const float*)d_in[5];
  const float* qw     = (const float*)d_in[6];
  const float* kw     = (const float*)d_in[7];

  us* hb  = (us*)d_ws;                          // [2048][4096]
  us* wb  = hb + (long)2048 * 4096;             // [10240][4096] (Wq|Wk|Wv|Wo)
  us* qkv = wb + (long)10240 * 4096;            // [2048][6144]
  us* ao  = qkv + (long)2048 * 6144;            // [2048][4096]

  // fused convert: hidden|Wq|Wk|Wv|Wo -> contiguous bf16 at hb
  cvt_all_k<<<24576, 256, 0, stream>>>(hidden, Wq, Wk, Wv, Wo, hb);

  // fused QKV projection: [2048,4096] x [6144,4096]^T -> bf16 [2048,6144]
  gemm8p<false><<<192, 512, 0, stream>>>(hb, wb, qkv, 4096, 6144, 24);

  // per-head RMSNorm + RoPE in place
  rms_rope_k<<<20480, 256, 0, stream>>>(qkv, fc, qw, kw);

  // flash attention -> bf16 [2048][4096]
  attn_k<<<1024, 256, 0, stream>>>(qkv, ao);

  // output projection -> f32 d_out
  gemm8p<true><<<128, 512, 0, stream>>>(ao, wb + (long)6144 * 4096, d_out,
                                        4096, 4096, 16);
}

// Round 4
// 354.406 us; speedup vs baseline: 1.1298x; 1.1218x over previous
//
#include <hip/hip_runtime.h>

// ---------------------------------------------------------------------------
// Qwen3-style attention block on MI355X (gfx950), bf16 MFMA pipeline.
// B=2, S=1024, HID=4096, H=32, KV=8, D=128.
// Stages: cvt(h,Wq,Wk,Wv) -> QKV GEMM (+Wo-cvt tail blocks) -> RMSNorm+RoPE
//         -> flash attn -> out GEMM (split-K x2, 256 blocks) -> add partials.
// GEMM core: m201 8-phase template, BM=BN=256, BK=64, 8 waves (2Mx4N),
// 24 ds_read_b128/K-tile (b0 frags resident), 1 half-tile staged per phase
// into the just-freed slot, counted vmcnt(6) once per K-tile, setprio,
// conflict-free chunk-XOR LDS swizzle (pre-swizzled global source).
// ---------------------------------------------------------------------------

typedef __attribute__((ext_vector_type(8))) short s8v;            // 8 bf16 (4 VGPR)
typedef __attribute__((ext_vector_type(4))) float f4v;
typedef __attribute__((ext_vector_type(8))) unsigned short u8v;
typedef __attribute__((ext_vector_type(4))) float float4v;
typedef unsigned short us;

#define SB() __builtin_amdgcn_sched_barrier(0)

__device__ __forceinline__ void BARRIER() {
  asm volatile("" ::: "memory");
  __builtin_amdgcn_s_barrier();
  asm volatile("" ::: "memory");
}

__device__ __forceinline__ us f2b(float f) {
  unsigned u = __builtin_bit_cast(unsigned, f);
  u += 0x7fffu + ((u >> 16) & 1u);            // round-to-nearest-even
  return (us)(u >> 16);
}
__device__ __forceinline__ float b2f(us h) {
  return __builtin_bit_cast(float, (unsigned)h << 16);
}

__device__ __forceinline__ void gload16(const void* g, void* l) {
  __builtin_amdgcn_global_load_lds(
      (const __attribute__((address_space(1))) unsigned int*)g,
      (__attribute__((address_space(3))) unsigned int*)l, 16, 0, 0);
}

// ---------------------------------------------------------------------------
// Fused f32 -> bf16 convert: hidden|Wq|Wk|Wv, contiguous bf16 destination.
// Block = 2048 elems. Ranges: hidden 4096 | Wq 8192 | Wk 2048 | Wv 2048.
// ---------------------------------------------------------------------------
__global__ __launch_bounds__(256) void cvt_all_k(const float* __restrict__ h,
                                                 const float* __restrict__ wq,
                                                 const float* __restrict__ wk,
                                                 const float* __restrict__ wv,
                                                 us* __restrict__ dst) {
  long blk = blockIdx.x;
  const float* src;
  long off;
  if (blk < 4096)        { src = h;  off = 0; }
  else if (blk < 12288)  { src = wq; off = 4096; }
  else if (blk < 14336)  { src = wk; off = 12288; }
  else                   { src = wv; off = 14336; }
  long i = (blk - off) * 2048 + (long)threadIdx.x * 8;
  long o = blk * 2048 + (long)threadIdx.x * 8;
  float4v a = *(const float4v*)(src + i);
  float4v b = *(const float4v*)(src + i + 4);
  u8v v;
  v[0] = f2b(a[0]); v[1] = f2b(a[1]); v[2] = f2b(a[2]); v[3] = f2b(a[3]);
  v[4] = f2b(b[0]); v[5] = f2b(b[1]); v[6] = f2b(b[2]); v[7] = f2b(b[3]);
  *(u8v*)(dst + o) = v;
}

// ---------------------------------------------------------------------------
// out = p[0..n) + p[n..2n)  (f32, 8 elems/thread, exact grid)
// ---------------------------------------------------------------------------
__global__ __launch_bounds__(256) void add2_k(const float* __restrict__ p,
                                              float* __restrict__ out, long n) {
  long i = ((long)blockIdx.x * 256 + threadIdx.x) * 8;
  float4v a0 = *(const float4v*)(p + i);
  float4v b0 = *(const float4v*)(p + i + 4);
  float4v a1 = *(const float4v*)(p + n + i);
  float4v b1 = *(const float4v*)(p + n + i + 4);
  float4v ra, rb;
#pragma unroll
  for (int k = 0; k < 4; ++k) { ra[k] = a0[k] + a1[k]; rb[k] = b0[k] + b1[k]; }
  *(float4v*)(out + i) = ra;
  *(float4v*)(out + i + 4) = rb;
}

// ---------------------------------------------------------------------------
// m201-style 8-phase bf16 GEMM: C[M,N](+K-split) = A[M,K] * W[N,K]^T
// 256x256 tile, BK=64, 512 threads (8 waves, 2M x 4N).
// LDS: [2 dbuf][2 half][128x64] for A and B = 128 KiB.
// Phases/K-tile: q(0,0) q(0,1) q(1,1) q(1,0); ds_reads 12,4,8,0 (b0 resident);
// stage one half-tile per phase into the slot freed the previous phase;
// vmcnt(6) once per K-tile (3 half-tiles in flight).
// SPLITK: grid 256 = 2 K-halves x (8 M x 16 N); writes f32 partials.
// CVTTAIL: blocks >= nGemm convert csrc(f32) -> cdst(bf16), 16.8M elems.
// ---------------------------------------------------------------------------
template <bool F32OUT, bool SPLITK, bool CVTTAIL>
__global__ __launch_bounds__(512, 2) void gemm8p(const us* __restrict__ A,
                                                 const us* __restrict__ W,
                                                 void* __restrict__ Cv,
                                                 int Kfull, int nkt, int ldc,
                                                 int NX, int nGemm,
                                                 const float* __restrict__ csrc,
                                                 us* __restrict__ cdst) {
  if constexpr (CVTTAIL) {
    if ((int)blockIdx.x >= nGemm) {
      long c = (long)((int)blockIdx.x - nGemm) * 512 + threadIdx.x;
      for (; c < 2097152; c += 64 * 512) {      // 16,777,216 elems / 8
        long i = c * 8;
        float4v x = *(const float4v*)(csrc + i);
        float4v y = *(const float4v*)(csrc + i + 4);
        u8v v;
        v[0] = f2b(x[0]); v[1] = f2b(x[1]); v[2] = f2b(x[2]); v[3] = f2b(x[3]);
        v[4] = f2b(y[0]); v[5] = f2b(y[1]); v[6] = f2b(y[2]); v[7] = f2b(y[3]);
        *(u8v*)(cdst + i) = v;
      }
      return;
    }
  }

  __shared__ __align__(16) us Ah[2][2][128 * 64];
  __shared__ __align__(16) us Bh[2][2][128 * 64];
  const int tid = threadIdx.x, lane = tid & 63, w = tid >> 6;
  const int wr = w >> 2, wc = w & 3;
  const int lr = lane & 15, lg = lane >> 4;

  // XCD-chunked bijective swizzle over the gemm blocks (nGemm % 8 == 0)
  const int cpx = nGemm >> 3;
  const int swz = ((int)blockIdx.x & 7) * cpx + ((int)blockIdx.x >> 3);
  long m0, n0, koff = 0;
  float* Cks = (float*)Cv;
  if constexpr (SPLITK) {
    const int ks = swz >> 7;                 // 128 blocks per K-half
    const int r = swz & 127;
    m0 = (long)(r >> 4) * 256;               // 8 M-tiles
    n0 = (long)(r & 15) * 256;               // 16 N-tiles
    koff = (long)ks * nkt * 64;
    Cks += (long)ks * 2048 * 4096;
  } else {
    m0 = (long)(swz / NX) * 256;
    n0 = (long)(swz % NX) * 256;
  }

  // staging geometry: thread covers 16B chunks c0, c1 of a 128x64 half-tile
  const int c0 = tid, c1 = 512 + tid;
  const int r0 = c0 >> 3, r1 = c1 >> 3;
  const int s0 = ((c0 & 7) ^ (r0 & 7)) << 3;       // inverse-swizzled src col
  const int s1 = ((c1 & 7) ^ (r1 & 7)) << 3;

#define STG(dst, src)                                                   \
  do {                                                                  \
    const us* _s = (src);                                               \
    us* _d = (dst);                                                     \
    gload16(_s + (long)r0 * Kfull + s0, _d + c0 * 8);                   \
    gload16(_s + (long)r1 * Kfull + s1, _d + c1 * 8);                   \
  } while (0)

  const us* Asrc = A + m0 * Kfull + koff;
  const us* Bsrc = W + n0 * Kfull + koff;
  const long hK = (long)128 * Kfull;

  // fragment read offsets (elements; row*64 + swizzled-chunk*8)
  const int ra = wr * 64 + lr, rb = wc * 32 + lr;
  const int offA0 = ra * 64 + ((lg ^ (ra & 7)) << 3);
  const int offA1 = ra * 64 + (((4 + lg) ^ (ra & 7)) << 3);
  const int offB0 = rb * 64 + ((lg ^ (rb & 7)) << 3);
  const int offB1 = rb * 64 + (((4 + lg) ^ (rb & 7)) << 3);

  f4v acc[8][4];
#pragma unroll
  for (int i = 0; i < 8; ++i)
#pragma unroll
    for (int j = 0; j < 4; ++j) acc[i][j] = (f4v){0.f, 0.f, 0.f, 0.f};

  const int nk = nkt;

  // prologue: tile0 {A0,B0,B1,A1} (8 loads) then tile1 {A0,B1,A1} (6 loads)
  STG(Ah[0][0], Asrc);
  STG(Bh[0][0], Bsrc);
  STG(Bh[0][1], Bsrc + hK);
  STG(Ah[0][1], Asrc + hK);
  STG(Ah[1][0], Asrc + 64);
  STG(Bh[1][1], Bsrc + hK + 64);
  STG(Ah[1][1], Asrc + hK + 64);
  asm volatile("s_waitcnt vmcnt(6)" ::: "memory");   // tile 0 landed
  BARRIER();

  s8v a[4][2], b0[2][2], b1[2][2];

#define RD_A(H)                                                         \
  _Pragma("unroll") for (int f = 0; f < 4; ++f) {                       \
    a[f][0] = *(const s8v*)(&Ah[d][H][offA0 + f * 1024]);               \
    a[f][1] = *(const s8v*)(&Ah[d][H][offA1 + f * 1024]);               \
  }
#define RD_B(BB, H)                                                     \
  _Pragma("unroll") for (int g = 0; g < 2; ++g) {                       \
    BB[g][0] = *(const s8v*)(&Bh[d][H][offB0 + g * 1024]);              \
    BB[g][1] = *(const s8v*)(&Bh[d][H][offB1 + g * 1024]);              \
  }
#define QUAD(QM, QN, BB)                                                \
  __builtin_amdgcn_s_setprio(1);                                        \
  _Pragma("unroll") for (int f = 0; f < 4; ++f)                         \
  _Pragma("unroll") for (int g = 0; g < 2; ++g) {                       \
    f4v t = acc[QM * 4 + f][QN * 2 + g];                                \
    t = __builtin_amdgcn_mfma_f32_16x16x32_bf16(a[f][0], BB[g][0], t, 0, 0, 0); \
    t = __builtin_amdgcn_mfma_f32_16x16x32_bf16(a[f][1], BB[g][1], t, 0, 0, 0); \
    acc[QM * 4 + f][QN * 2 + g] = t;                                    \
  }                                                                     \
  __builtin_amdgcn_s_setprio(0);
#define PREMFMA()                                                       \
  BARRIER();                                                            \
  asm volatile("s_waitcnt lgkmcnt(0)" ::: "memory");                    \
  SB();

  for (int kt = 0; kt < nk; ++kt) {
    const int d = kt & 1;
    const long kb2 = (long)(kt + 2) * 64;
    const bool p1 = (kt + 1 < nk), p2 = (kt + 2 < nk);

    // ---- phase 1: q(0,0); reads A0(8)+B0(4); stage B0(kt+1) -> other dbuf ----
    RD_A(0)
    RD_B(b0, 0)
    if (p1) STG(Bh[d ^ 1][0], Bsrc + (long)(kt + 1) * 64);
    PREMFMA()
    QUAD(0, 0, b0)
    SB(); BARRIER();

    // ---- phase 2: q(0,1); reads B1(4); stage A0(kt+2) into freed A0 slot ----
    RD_B(b1, 1)
    if (p2) STG(Ah[d][0], Asrc + kb2);
    PREMFMA()
    QUAD(0, 1, b1)
    SB(); BARRIER();

    // ---- phase 3: q(1,1); reads A1(8); stage B1(kt+2) into freed B1 slot ----
    RD_A(1)
    if (p2) STG(Bh[d][1], Bsrc + hK + kb2);
    PREMFMA()
    QUAD(1, 1, b1)
    SB(); BARRIER();

    // ---- phase 4: q(1,0); no reads; stage A1(kt+2); counted vmcnt ----
    if (p2) STG(Ah[d][1], Asrc + hK + kb2);
    PREMFMA()
    QUAD(1, 0, b0)
    SB();
    if (p2) asm volatile("s_waitcnt vmcnt(6)" ::: "memory");
    else    asm volatile("s_waitcnt vmcnt(0)" ::: "memory");
    BARRIER();
  }

  // ---- epilogue ----
#pragma unroll
  for (int qm = 0; qm < 2; ++qm)
#pragma unroll
    for (int f = 0; f < 4; ++f) {
      long row = m0 + qm * 128 + wr * 64 + f * 16 + lg * 4;
#pragma unroll
      for (int qn = 0; qn < 2; ++qn)
#pragma unroll
        for (int g = 0; g < 2; ++g) {
          long col = n0 + qn * 128 + wc * 32 + g * 16 + lr;
          f4v v = acc[qm * 4 + f][qn * 2 + g];
          if constexpr (F32OUT) {
#pragma unroll
            for (int r = 0; r < 4; ++r) Cks[(row + r) * ldc + col] = v[r];
          } else {
            us* C = (us*)Cv;
#pragma unroll
            for (int r = 0; r < 4; ++r) C[(row + r) * ldc + col] = f2b(v[r]);
          }
        }
    }
#undef STG
#undef RD_A
#undef RD_B
#undef QUAD
#undef PREMFMA
}

// ---------------------------------------------------------------------------
// Per-head RMSNorm (D=128) + RoPE, in-place on the bf16 qkv buffer.
// ---------------------------------------------------------------------------
__global__ __launch_bounds__(256) void rms_rope_k(us* __restrict__ qkv,
                                                  const float* __restrict__ fc,
                                                  const float* __restrict__ qw,
                                                  const float* __restrict__ kw) {
  int idx = blockIdx.x * 4 + (threadIdx.x >> 6);
  int lane = threadIdx.x & 63;
  int head = idx % 40;                 // 0..31 = Q heads, 32..39 = K heads
  int row = idx / 40;                  // b*1024 + s
  int s = row & 1023;
  us* p;
  const float* w;
  if (head < 32) { p = qkv + (long)row * 6144 + head * 128; w = qw; }
  else           { p = qkv + (long)row * 6144 + 4096 + (head - 32) * 128; w = kw; }
  float x0 = b2f(p[lane]), x1 = b2f(p[lane + 64]);
  float ss = x0 * x0 + x1 * x1;
#pragma unroll
  for (int off = 32; off; off >>= 1) ss += __shfl_xor(ss, off);
  float r = rsqrtf(ss * (1.0f / 128.0f) + 1e-6f);
  float y0 = x0 * r * w[lane], y1 = x1 * r * w[lane + 64];
  const float* cosp = fc + (long)s * 128;
  const float* sinp = cosp + 1024 * 128;
  const float* nsinp = sinp + 1024 * 128;
  float e0 = y0 * cosp[lane] + y1 * nsinp[lane];
  float e1 = y1 * cosp[lane + 64] + y0 * sinp[lane + 64];
  p[lane] = f2b(e0);
  p[lane + 64] = f2b(e1);
}

// ---------------------------------------------------------------------------
// Flash attention (no mask), GQA 4:1. Block = 4 waves = 64 q-rows; 64-key tiles.
// ---------------------------------------------------------------------------
__global__ __launch_bounds__(256) void attn_k(const us* __restrict__ qkv,
                                              us* __restrict__ ao) {
  __shared__ us Kt[64 * 128];   // [key][d], rows 256B, XOR-swizzled
  __shared__ us Vt[128 * 72];   // [d][key], padded rows (144B)
  __shared__ us Pl[4 * 1024];   // per-wave 16x64 P, XOR-swizzled

  const int bid = blockIdx.x;
  const int qt = bid & 15;
  const int h = (bid >> 4) & 31;
  const int b = bid >> 9;
  const int kvh = h >> 2;
  const int tid = threadIdx.x, lane = tid & 63, w = tid >> 6;
  const int lr = lane & 15, lg = lane >> 4;

  const us* Qb =
      qkv + (long)(b * 1024 + qt * 64 + w * 16 + lr) * 6144 + h * 128;
  s8v qf[4];
#pragma unroll
  for (int ks = 0; ks < 4; ++ks) qf[ks] = *(const s8v*)(Qb + ks * 32 + lg * 8);

  f4v o[8];
#pragma unroll
  for (int n = 0; n < 8; ++n) o[n] = (f4v){0.f, 0.f, 0.f, 0.f};
  float m[4], l[4];
#pragma unroll
  for (int r = 0; r < 4; ++r) { m[r] = -1e30f; l[r] = 0.f; }

  const float SL = 0.08838834764831845f * 1.4426950408889634f;  // D^-1/2 * log2e
  const long krow = (long)b * 1024 * 6144 + 4096 + kvh * 128;
  const long vrow = (long)b * 1024 * 6144 + 5120 + kvh * 128;

  for (int kt = 0; kt < 16; ++kt) {
    __syncthreads();
#pragma unroll
    for (int t = 0; t < 4; ++t) {
      int c = t * 256 + tid;
      int row = c >> 4;
      int sc = (c & 15) ^ (row & 7);
      gload16(qkv + krow + (long)(kt * 64 + row) * 6144 + sc * 8, &Kt[c * 8]);
    }
#pragma unroll
    for (int t = 0; t < 4; ++t) {
      int c = t * 256 + tid;
      int key = c & 63;
      int d0 = (c >> 6) * 8;
      s8v v = *(const s8v*)(qkv + vrow + (long)(kt * 64 + key) * 6144 + d0);
#pragma unroll
      for (int i = 0; i < 8; ++i) Vt[(d0 + i) * 72 + key] = (us)v[i];
    }
    __syncthreads();

    f4v sacc[4];
#pragma unroll
    for (int j = 0; j < 4; ++j) sacc[j] = (f4v){0.f, 0.f, 0.f, 0.f};
    __builtin_amdgcn_s_setprio(1);
#pragma unroll
    for (int ks = 0; ks < 4; ++ks) {
#pragma unroll
      for (int j = 0; j < 4; ++j) {
        int key = j * 16 + lr;
        s8v kf = *(const s8v*)&Kt[key * 128 + (((ks * 64 + lg * 16) ^ ((key & 7) << 4)) >> 1)];
        sacc[j] = __builtin_amdgcn_mfma_f32_16x16x32_bf16(qf[ks], kf, sacc[j], 0, 0, 0);
      }
    }
    __builtin_amdgcn_s_setprio(0);

    float sm[4];
#pragma unroll
    for (int r = 0; r < 4; ++r)
      sm[r] = fmaxf(fmaxf(sacc[0][r], sacc[1][r]), fmaxf(sacc[2][r], sacc[3][r]));
#pragma unroll
    for (int off = 1; off < 16; off <<= 1)
#pragma unroll
      for (int r = 0; r < 4; ++r) sm[r] = fmaxf(sm[r], __shfl_xor(sm[r], off));
    float alpha[4];
#pragma unroll
    for (int r = 0; r < 4; ++r) {
      float nm = fmaxf(m[r], sm[r] * SL);
      alpha[r] = exp2f(m[r] - nm);
      m[r] = nm;
      l[r] *= alpha[r];
    }
#pragma unroll
    for (int n = 0; n < 8; ++n)
#pragma unroll
      for (int r = 0; r < 4; ++r) o[n][r] *= alpha[r];

    us* pw = Pl + w * 1024;
#pragma unroll
    for (int j = 0; j < 4; ++j)
#pragma unroll
      for (int r = 0; r < 4; ++r) {
        float p = exp2f(sacc[j][r] * SL - m[r]);
        l[r] += p;
        int prow = lg * 4 + r, pcol = j * 16 + lr;
        pw[(prow * 128 + ((pcol * 2) ^ ((prow & 7) << 4))) >> 1] = f2b(p);
      }

    __builtin_amdgcn_s_setprio(1);
#pragma unroll
    for (int ks = 0; ks < 2; ++ks) {
      int bo = ks * 64 + lg * 16;
      s8v pf = *(const s8v*)&Pl[w * 1024 + ((lr * 128 + (bo ^ ((lr & 7) << 4))) >> 1)];
#pragma unroll
      for (int n = 0; n < 8; ++n) {
        s8v vf = *(const s8v*)&Vt[(n * 16 + lr) * 72 + ks * 32 + lg * 8];
        o[n] = __builtin_amdgcn_mfma_f32_16x16x32_bf16(pf, vf, o[n], 0, 0, 0);
      }
    }
    __builtin_amdgcn_s_setprio(0);
  }

#pragma unroll
  for (int off = 1; off < 16; off <<= 1)
#pragma unroll
    for (int r = 0; r < 4; ++r) l[r] += __shfl_xor(l[r], off);
  float inv[4];
#pragma unroll
  for (int r = 0; r < 4; ++r) inv[r] = 1.f / l[r];
  const long ob = (long)(b * 1024 + qt * 64 + w * 16) * 4096 + h * 128;
#pragma unroll
  for (int n = 0; n < 8; ++n)
#pragma unroll
    for (int r = 0; r < 4; ++r)
      ao[ob + (long)(lg * 4 + r) * 4096 + n * 16 + lr] = f2b(o[n][r] * inv[r]);
}

// ---------------------------------------------------------------------------
// Launch
// ---------------------------------------------------------------------------
extern "C" void kernel_launch(void* const* d_in, const int* in_sizes, int n_in,
                              void* d_out, int out_size, void* d_ws, size_t ws_size,
                              hipStream_t stream) {
  const float* hidden = (const float*)d_in[0];
  const float* fc     = (const float*)d_in[1];
  const float* Wq     = (const float*)d_in[2];
  const float* Wk     = (const float*)d_in[3];
  const float* Wv     = (const float*)d_in[4];
  const float* Wo     = (const float*)d_in[5];
  const float* qw     = (const float*)d_in[6];
  const float* kw     = (const float*)d_in[7];

  us* hb  = (us*)d_ws;                          // [2048][4096] bf16
  us* wb  = hb + (long)2048 * 4096;             // [10240][4096] bf16 (Wq|Wk|Wv|Wo)
  us* wbo = wb + (long)6144 * 4096;             // Wo bf16 [4096][4096]
  us* qkv = wbo + (long)4096 * 4096;            // [2048][6144] bf16
  us* ao  = qkv + (long)2048 * 6144;            // [2048][4096] bf16
  // split-K partials (f32, 2 x 2048 x 4096 = 67.1 MB) overlay hb..Wv region,
  // which is dead by the time the out-proj gemm runs.
  float* part = (float*)d_ws;

  // convert hidden|Wq|Wk|Wv -> contiguous bf16 at hb (Wo handled in-gemm)
  cvt_all_k<<<16384, 256, 0, stream>>>(hidden, Wq, Wk, Wv, hb);

  // fused QKV projection (192 gemm blocks) + Wo convert (64 tail blocks)
  gemm8p<false, false, true><<<256, 512, 0, stream>>>(
      hb, wb, qkv, 4096, 64, 6144, 24, 192, Wo, wbo);

  // per-head RMSNorm + RoPE in place
  rms_rope_k<<<20480, 256, 0, stream>>>(qkv, fc, qw, kw);

  // flash attention -> bf16 [2048][4096]
  attn_k<<<1024, 256, 0, stream>>>(qkv, ao);

  // output projection, split-K x2 -> f32 partials (256 blocks, full chip)
  gemm8p<true, true, false><<<256, 512, 0, stream>>>(
      ao, wbo, part, 4096, 32, 4096, 16, 256, nullptr, nullptr);

  // sum partials -> d_out
  add2_k<<<4096, 256, 0, stream>>>(part, (float*)d_out, (long)2048 * 4096);
}

// Round 5
// 345.228 us; speedup vs baseline: 1.1598x; 1.0266x over previous
//
#include <hip/hip_runtime.h>

// ---------------------------------------------------------------------------
// Qwen3-style attention block on MI355X (gfx950), bf16 MFMA pipeline.
// B=2, S=1024, HID=4096, H=32, KV=8, D=128.
// Stages: cvt(h,Wq,Wk,Wv) -> QKV GEMM (+Wo-cvt tail) -> RMSNorm+RoPE
//         -> flash attn -> out GEMM (BM=128, 256 blocks, full-K, no split).
// GEMM core: m201 8-phase template, BN=256, BK=64, 8 waves (2Mx4N),
// templated A-half height AH (128 for QKV, 64 for out-proj), one half-tile
// staged per phase into the just-freed slot, counted vmcnt(2*LA+2) once per
// K-tile, setprio, conflict-free chunk-XOR LDS swizzle, 2D XCD chunking.
// ---------------------------------------------------------------------------

typedef __attribute__((ext_vector_type(8))) short s8v;            // 8 bf16 (4 VGPR)
typedef __attribute__((ext_vector_type(4))) float f4v;
typedef __attribute__((ext_vector_type(8))) unsigned short u8v;
typedef __attribute__((ext_vector_type(4))) float float4v;
typedef __attribute__((ext_vector_type(2))) float float2v;
typedef unsigned short us;

#define SB() __builtin_amdgcn_sched_barrier(0)

__device__ __forceinline__ void BARRIER() {
  asm volatile("" ::: "memory");
  __builtin_amdgcn_s_barrier();
  asm volatile("" ::: "memory");
}

__device__ __forceinline__ us f2b(float f) {
  unsigned u = __builtin_bit_cast(unsigned, f);
  u += 0x7fffu + ((u >> 16) & 1u);            // round-to-nearest-even
  return (us)(u >> 16);
}
__device__ __forceinline__ float b2f(us h) {
  return __builtin_bit_cast(float, (unsigned)h << 16);
}

__device__ __forceinline__ void gload16(const void* g, void* l) {
  __builtin_amdgcn_global_load_lds(
      (const __attribute__((address_space(1))) unsigned int*)g,
      (__attribute__((address_space(3))) unsigned int*)l, 16, 0, 0);
}

// ---------------------------------------------------------------------------
// Fused f32 -> bf16 convert: hidden|Wq|Wk|Wv, contiguous bf16 destination.
// Block = 2048 elems. Ranges: hidden 4096 | Wq 8192 | Wk 2048 | Wv 2048.
// ---------------------------------------------------------------------------
__global__ __launch_bounds__(256) void cvt_all_k(const float* __restrict__ h,
                                                 const float* __restrict__ wq,
                                                 const float* __restrict__ wk,
                                                 const float* __restrict__ wv,
                                                 us* __restrict__ dst) {
  long blk = blockIdx.x;
  const float* src;
  long off;
  if (blk < 4096)        { src = h;  off = 0; }
  else if (blk < 12288)  { src = wq; off = 4096; }
  else if (blk < 14336)  { src = wk; off = 12288; }
  else                   { src = wv; off = 14336; }
  long i = (blk - off) * 2048 + (long)threadIdx.x * 8;
  long o = blk * 2048 + (long)threadIdx.x * 8;
  float4v a = *(const float4v*)(src + i);
  float4v b = *(const float4v*)(src + i + 4);
  u8v v;
  v[0] = f2b(a[0]); v[1] = f2b(a[1]); v[2] = f2b(a[2]); v[3] = f2b(a[3]);
  v[4] = f2b(b[0]); v[5] = f2b(b[1]); v[6] = f2b(b[2]); v[7] = f2b(b[3]);
  *(u8v*)(dst + o) = v;
}

// ---------------------------------------------------------------------------
// m201-style 8-phase bf16 GEMM: C[M,N] = A[M,K] * W[N,K]^T
// Tile = (2*AH) x 256, BK=64, 512 threads (8 waves, 2M x 4N).
// LDS: A[2][2][AH*64] + B[2][2][128*64]; AH=128 -> 128 KiB, AH=64 -> 96 KiB.
// Phases/K-tile: q(0,0) q(0,1) q(1,1) q(1,0); b0 frags resident (phase 4 has
// no ds_reads); one half-tile staged per phase into the just-freed slot;
// counted vmcnt(2*LA+2) once per K-tile (3 half-tiles in flight).
// Grid mapping: 2D XCD chunks (cm x cn tiles per XCD), M-fastest in chunk.
// CVTTAIL (QKV): blocks >= nGemm convert csrc f32 -> cdst bf16 (16.8M elems).
// ---------------------------------------------------------------------------
template <int AH, bool F32OUT, bool CVTTAIL>
__global__ __launch_bounds__(512, 2) void gemm8p(const us* __restrict__ A,
                                                 const us* __restrict__ W,
                                                 void* __restrict__ Cv,
                                                 int K, int nkt, int ldc,
                                                 int cm, int cn, int ncn,
                                                 int nGemm,
                                                 const float* __restrict__ csrc,
                                                 us* __restrict__ cdst) {
  if constexpr (CVTTAIL) {
    if ((int)blockIdx.x >= nGemm) {
      long c = (long)((int)blockIdx.x - nGemm) * 512 + threadIdx.x;
      for (; c < 2097152; c += 64 * 512) {      // 16,777,216 elems / 8
        long i = c * 8;
        float4v x = *(const float4v*)(csrc + i);
        float4v y = *(const float4v*)(csrc + i + 4);
        u8v v;
        v[0] = f2b(x[0]); v[1] = f2b(x[1]); v[2] = f2b(x[2]); v[3] = f2b(x[3]);
        v[4] = f2b(y[0]); v[5] = f2b(y[1]); v[6] = f2b(y[2]); v[7] = f2b(y[3]);
        *(u8v*)(cdst + i) = v;
      }
      return;
    }
  }

  constexpr int FR = AH / 32;          // A row-frags per wave per half
  constexpr int LA = AH / 64;          // gload_lds per thread per A-half
  constexpr int VM = 2 * LA + 2;       // counted vmcnt (keep kt+2's loads)

  __shared__ __align__(16) us Ah[2][2][AH * 64];
  __shared__ __align__(16) us Bh[2][2][128 * 64];
  const int tid = threadIdx.x, lane = tid & 63, w = tid >> 6;
  const int wr = w >> 2, wc = w & 3;
  const int lr = lane & 15, lg = lane >> 4;

  // 2D XCD chunking: xcd = bid&7 owns a cm x cn tile chunk, M-fastest inside.
  const int xcd = (int)blockIdx.x & 7;
  const int i2 = (int)blockIdx.x >> 3;
  const int im = i2 % cm, itn = i2 / cm;
  const long m0 = (long)((xcd / ncn) * cm + im) * (2 * AH);
  const long n0 = (long)((xcd % ncn) * cn + itn) * 256;

  // staging geometry: thread covers 16B chunk(s) l*512+tid of a half-tile
  const int rA0 = tid >> 3;                        // row for chunk l=0
  const int sc0 = ((tid & 7) ^ (rA0 & 7)) << 3;    // inverse-swizzled src col

#define STGH(dst, src, LOADS)                                           \
  do {                                                                  \
    const us* _s = (src);                                               \
    us* _d = (dst);                                                     \
    _Pragma("unroll") for (int l = 0; l < (LOADS); ++l)                 \
      gload16(_s + (long)(rA0 + l * 64) * K + sc0, _d + (l * 512 + tid) * 8); \
  } while (0)

  const us* Asrc = A + m0 * K;     // half h at + h*AH*K, K-tile kt at + kt*64
  const us* Bsrc = W + n0 * K;
  const long hKA = (long)AH * K;
  const long hKB = (long)128 * K;

  // fragment read offsets (elements; row*64 + swizzled-chunk*8)
  const int ra = wr * (AH / 2) + lr, rb = wc * 32 + lr;
  const int offA0 = ra * 64 + ((lg ^ (ra & 7)) << 3);
  const int offA1 = ra * 64 + (((4 + lg) ^ (ra & 7)) << 3);
  const int offB0 = rb * 64 + ((lg ^ (rb & 7)) << 3);
  const int offB1 = rb * 64 + (((4 + lg) ^ (rb & 7)) << 3);

  f4v acc[2 * FR][4];
#pragma unroll
  for (int i = 0; i < 2 * FR; ++i)
#pragma unroll
    for (int j = 0; j < 4; ++j) acc[i][j] = (f4v){0.f, 0.f, 0.f, 0.f};

  const int nk = nkt;

  // prologue: tile0 {A0,B0,B1,A1} then tile1 {A0,B1,A1}
  STGH(Ah[0][0], Asrc, LA);
  STGH(Bh[0][0], Bsrc, 2);
  STGH(Bh[0][1], Bsrc + hKB, 2);
  STGH(Ah[0][1], Asrc + hKA, LA);
  STGH(Ah[1][0], Asrc + 64, LA);
  STGH(Bh[1][1], Bsrc + hKB + 64, 2);
  STGH(Ah[1][1], Asrc + hKA + 64, LA);
  asm volatile("s_waitcnt vmcnt(%0)" :: "i"(VM) : "memory");   // tile 0 landed
  BARRIER();

  s8v a[FR][2], b0[2][2], b1[2][2];

#define RD_A(H)                                                         \
  _Pragma("unroll") for (int f = 0; f < FR; ++f) {                      \
    a[f][0] = *(const s8v*)(&Ah[d][H][offA0 + f * 1024]);               \
    a[f][1] = *(const s8v*)(&Ah[d][H][offA1 + f * 1024]);               \
  }
#define RD_B(BB, H)                                                     \
  _Pragma("unroll") for (int g = 0; g < 2; ++g) {                       \
    BB[g][0] = *(const s8v*)(&Bh[d][H][offB0 + g * 1024]);              \
    BB[g][1] = *(const s8v*)(&Bh[d][H][offB1 + g * 1024]);              \
  }
#define QUAD(QM, QN, BB)                                                \
  __builtin_amdgcn_s_setprio(1);                                        \
  _Pragma("unroll") for (int f = 0; f < FR; ++f)                        \
  _Pragma("unroll") for (int g = 0; g < 2; ++g) {                       \
    f4v t = acc[QM * FR + f][QN * 2 + g];                               \
    t = __builtin_amdgcn_mfma_f32_16x16x32_bf16(a[f][0], BB[g][0], t, 0, 0, 0); \
    t = __builtin_amdgcn_mfma_f32_16x16x32_bf16(a[f][1], BB[g][1], t, 0, 0, 0); \
    acc[QM * FR + f][QN * 2 + g] = t;                                   \
  }                                                                     \
  __builtin_amdgcn_s_setprio(0);
#define PREMFMA()                                                       \
  BARRIER();                                                            \
  asm volatile("s_waitcnt lgkmcnt(0)" ::: "memory");                    \
  SB();

  for (int kt = 0; kt < nk; ++kt) {
    const int d = kt & 1;
    const long kb2 = (long)(kt + 2) * 64;
    const bool p1 = (kt + 1 < nk), p2 = (kt + 2 < nk);

    // ---- phase 1: q(0,0); stage B0(kt+1) -> other dbuf ----
    RD_A(0)
    RD_B(b0, 0)
    if (p1) STGH(Bh[d ^ 1][0], Bsrc + (long)(kt + 1) * 64, 2);
    PREMFMA()
    QUAD(0, 0, b0)
    SB(); BARRIER();

    // ---- phase 2: q(0,1); stage A0(kt+2) into freed A0 slot ----
    RD_B(b1, 1)
    if (p2) STGH(Ah[d][0], Asrc + kb2, LA);
    PREMFMA()
    QUAD(0, 1, b1)
    SB(); BARRIER();

    // ---- phase 3: q(1,1); stage B1(kt+2) into freed B1 slot ----
    RD_A(1)
    if (p2) STGH(Bh[d][1], Bsrc + hKB + kb2, 2);
    PREMFMA()
    QUAD(1, 1, b1)
    SB(); BARRIER();

    // ---- phase 4: q(1,0); no ds_reads; stage A1(kt+2); counted vmcnt ----
    if (p2) STGH(Ah[d][1], Asrc + hKA + kb2, LA);
    PREMFMA()
    QUAD(1, 0, b0)
    SB();
    if (p2) asm volatile("s_waitcnt vmcnt(%0)" :: "i"(VM) : "memory");
    else    asm volatile("s_waitcnt vmcnt(0)" ::: "memory");
    BARRIER();
  }

  // ---- epilogue ----
#pragma unroll
  for (int qm = 0; qm < 2; ++qm)
#pragma unroll
    for (int f = 0; f < FR; ++f) {
      long row = m0 + qm * AH + wr * (AH / 2) + f * 16 + lg * 4;
#pragma unroll
      for (int qn = 0; qn < 2; ++qn)
#pragma unroll
        for (int g = 0; g < 2; ++g) {
          long col = n0 + qn * 128 + wc * 32 + g * 16 + lr;
          f4v v = acc[qm * FR + f][qn * 2 + g];
          if constexpr (F32OUT) {
            float* C = (float*)Cv;
#pragma unroll
            for (int r = 0; r < 4; ++r) C[(row + r) * ldc + col] = v[r];
          } else {
            us* C = (us*)Cv;
#pragma unroll
            for (int r = 0; r < 4; ++r) C[(row + r) * ldc + col] = f2b(v[r]);
          }
        }
    }
#undef STGH
#undef RD_A
#undef RD_B
#undef QUAD
#undef PREMFMA
}

// ---------------------------------------------------------------------------
// Per-head RMSNorm (D=128) + RoPE, in-place, vectorized (us2 / float2).
// One wave per (row, head); lane owns d = {2*lane, 2*lane+1}; the RoPE
// partner (d +/- 64) lives in lane^32 -> one shuffle pair.
// ---------------------------------------------------------------------------
__global__ __launch_bounds__(256) void rms_rope_k(us* __restrict__ qkv,
                                                  const float* __restrict__ fc,
                                                  const float* __restrict__ qw,
                                                  const float* __restrict__ kw) {
  int idx = blockIdx.x * 4 + (threadIdx.x >> 6);
  int lane = threadIdx.x & 63;
  int head = idx % 40;                 // 0..31 = Q heads, 32..39 = K heads
  int row = idx / 40;                  // b*1024 + s
  int s = row & 1023;
  us* p;
  const float* w;
  if (head < 32) { p = qkv + (long)row * 6144 + head * 128; w = qw; }
  else           { p = qkv + (long)row * 6144 + 4096 + (head - 32) * 128; w = kw; }

  unsigned v = ((const unsigned*)p)[lane];
  float x0 = b2f((us)(v & 0xffff)), x1 = b2f((us)(v >> 16));
  float ss = x0 * x0 + x1 * x1;
#pragma unroll
  for (int off = 32; off; off >>= 1) ss += __shfl_xor(ss, off);
  float r = rsqrtf(ss * (1.0f / 128.0f) + 1e-6f);
  float2v wv = ((const float2v*)w)[lane];
  float y0 = x0 * r * wv[0], y1 = x1 * r * wv[1];
  float py0 = __shfl(y0, lane ^ 32);
  float py1 = __shfl(y1, lane ^ 32);
  float2v cv = ((const float2v*)(fc + (long)s * 128))[lane];
  const float* sbase = (lane < 32) ? (fc + 2 * 1024 * 128) : (fc + 1024 * 128);
  float2v sv = ((const float2v*)(sbase + (long)s * 128))[lane];
  float e0 = y0 * cv[0] + py0 * sv[0];
  float e1 = y1 * cv[1] + py1 * sv[1];
  ((unsigned*)p)[lane] = (unsigned)f2b(e0) | ((unsigned)f2b(e1) << 16);
}

// ---------------------------------------------------------------------------
// Flash attention (no mask), GQA 4:1. Block = 4 waves = 64 q-rows; 64-key tiles.
// ---------------------------------------------------------------------------
__global__ __launch_bounds__(256) void attn_k(const us* __restrict__ qkv,
                                              us* __restrict__ ao) {
  __shared__ us Kt[64 * 128];   // [key][d], rows 256B, XOR-swizzled
  __shared__ us Vt[128 * 72];   // [d][key], padded rows (144B)
  __shared__ us Pl[4 * 1024];   // per-wave 16x64 P, XOR-swizzled

  const int bid = blockIdx.x;
  const int qt = bid & 15;
  const int h = (bid >> 4) & 31;
  const int b = bid >> 9;
  const int kvh = h >> 2;
  const int tid = threadIdx.x, lane = tid & 63, w = tid >> 6;
  const int lr = lane & 15, lg = lane >> 4;

  const us* Qb =
      qkv + (long)(b * 1024 + qt * 64 + w * 16 + lr) * 6144 + h * 128;
  s8v qf[4];
#pragma unroll
  for (int ks = 0; ks < 4; ++ks) qf[ks] = *(const s8v*)(Qb + ks * 32 + lg * 8);

  f4v o[8];
#pragma unroll
  for (int n = 0; n < 8; ++n) o[n] = (f4v){0.f, 0.f, 0.f, 0.f};
  float m[4], l[4];
#pragma unroll
  for (int r = 0; r < 4; ++r) { m[r] = -1e30f; l[r] = 0.f; }

  const float SL = 0.08838834764831845f * 1.4426950408889634f;  // D^-1/2 * log2e
  const long krow = (long)b * 1024 * 6144 + 4096 + kvh * 128;
  const long vrow = (long)b * 1024 * 6144 + 5120 + kvh * 128;

  for (int kt = 0; kt < 16; ++kt) {
    __syncthreads();
#pragma unroll
    for (int t = 0; t < 4; ++t) {
      int c = t * 256 + tid;
      int row = c >> 4;
      int sc = (c & 15) ^ (row & 7);
      gload16(qkv + krow + (long)(kt * 64 + row) * 6144 + sc * 8, &Kt[c * 8]);
    }
#pragma unroll
    for (int t = 0; t < 4; ++t) {
      int c = t * 256 + tid;
      int key = c & 63;
      int d0 = (c >> 6) * 8;
      s8v v = *(const s8v*)(qkv + vrow + (long)(kt * 64 + key) * 6144 + d0);
#pragma unroll
      for (int i = 0; i < 8; ++i) Vt[(d0 + i) * 72 + key] = (us)v[i];
    }
    __syncthreads();

    f4v sacc[4];
#pragma unroll
    for (int j = 0; j < 4; ++j) sacc[j] = (f4v){0.f, 0.f, 0.f, 0.f};
    __builtin_amdgcn_s_setprio(1);
#pragma unroll
    for (int ks = 0; ks < 4; ++ks) {
#pragma unroll
      for (int j = 0; j < 4; ++j) {
        int key = j * 16 + lr;
        s8v kf = *(const s8v*)&Kt[key * 128 + (((ks * 64 + lg * 16) ^ ((key & 7) << 4)) >> 1)];
        sacc[j] = __builtin_amdgcn_mfma_f32_16x16x32_bf16(qf[ks], kf, sacc[j], 0, 0, 0);
      }
    }
    __builtin_amdgcn_s_setprio(0);

    float sm[4];
#pragma unroll
    for (int r = 0; r < 4; ++r)
      sm[r] = fmaxf(fmaxf(sacc[0][r], sacc[1][r]), fmaxf(sacc[2][r], sacc[3][r]));
#pragma unroll
    for (int off = 1; off < 16; off <<= 1)
#pragma unroll
      for (int r = 0; r < 4; ++r) sm[r] = fmaxf(sm[r], __shfl_xor(sm[r], off));
    float alpha[4];
#pragma unroll
    for (int r = 0; r < 4; ++r) {
      float nm = fmaxf(m[r], sm[r] * SL);
      alpha[r] = exp2f(m[r] - nm);
      m[r] = nm;
      l[r] *= alpha[r];
    }
#pragma unroll
    for (int n = 0; n < 8; ++n)
#pragma unroll
      for (int r = 0; r < 4; ++r) o[n][r] *= alpha[r];

    us* pw = Pl + w * 1024;
#pragma unroll
    for (int j = 0; j < 4; ++j)
#pragma unroll
      for (int r = 0; r < 4; ++r) {
        float p = exp2f(sacc[j][r] * SL - m[r]);
        l[r] += p;
        int prow = lg * 4 + r, pcol = j * 16 + lr;
        pw[(prow * 128 + ((pcol * 2) ^ ((prow & 7) << 4))) >> 1] = f2b(p);
      }

    __builtin_amdgcn_s_setprio(1);
#pragma unroll
    for (int ks = 0; ks < 2; ++ks) {
      int bo = ks * 64 + lg * 16;
      s8v pf = *(const s8v*)&Pl[w * 1024 + ((lr * 128 + (bo ^ ((lr & 7) << 4))) >> 1)];
#pragma unroll
      for (int n = 0; n < 8; ++n) {
        s8v vf = *(const s8v*)&Vt[(n * 16 + lr) * 72 + ks * 32 + lg * 8];
        o[n] = __builtin_amdgcn_mfma_f32_16x16x32_bf16(pf, vf, o[n], 0, 0, 0);
      }
    }
    __builtin_amdgcn_s_setprio(0);
  }

#pragma unroll
  for (int off = 1; off < 16; off <<= 1)
#pragma unroll
    for (int r = 0; r < 4; ++r) l[r] += __shfl_xor(l[r], off);
  float inv[4];
#pragma unroll
  for (int r = 0; r < 4; ++r) inv[r] = 1.f / l[r];
  const long ob = (long)(b * 1024 + qt * 64 + w * 16) * 4096 + h * 128;
#pragma unroll
  for (int n = 0; n < 8; ++n)
#pragma unroll
    for (int r = 0; r < 4; ++r)
      ao[ob + (long)(lg * 4 + r) * 4096 + n * 16 + lr] = f2b(o[n][r] * inv[r]);
}

// ---------------------------------------------------------------------------
// Launch
// ---------------------------------------------------------------------------
extern "C" void kernel_launch(void* const* d_in, const int* in_sizes, int n_in,
                              void* d_out, int out_size, void* d_ws, size_t ws_size,
                              hipStream_t stream) {
  const float* hidden = (const float*)d_in[0];
  const float* fc     = (const float*)d_in[1];
  const float* Wq     = (const float*)d_in[2];
  const float* Wk     = (const float*)d_in[3];
  const float* Wv     = (const float*)d_in[4];
  const float* Wo     = (const float*)d_in[5];
  const float* qw     = (const float*)d_in[6];
  const float* kw     = (const float*)d_in[7];

  us* hb  = (us*)d_ws;                          // [2048][4096] bf16
  us* wb  = hb + (long)2048 * 4096;             // [10240][4096] bf16 (Wq|Wk|Wv|Wo)
  us* wbo = wb + (long)6144 * 4096;             // Wo bf16 [4096][4096]
  us* qkv = wbo + (long)4096 * 4096;            // [2048][6144] bf16
  us* ao  = qkv + (long)2048 * 6144;            // [2048][4096] bf16

  // convert hidden|Wq|Wk|Wv -> contiguous bf16 at hb (Wo converted in-gemm)
  cvt_all_k<<<16384, 256, 0, stream>>>(hidden, Wq, Wk, Wv, hb);

  // fused QKV projection (192 gemm blocks: 8M x 24N, XCD chunks 4Mx6N)
  // + Wo convert (64 tail blocks)
  gemm8p<128, false, true><<<256, 512, 0, stream>>>(
      hb, wb, qkv, 4096, 64, 6144, 4, 6, 4, 192, Wo, wbo);

  // per-head RMSNorm + RoPE in place
  rms_rope_k<<<20480, 256, 0, stream>>>(qkv, fc, qw, kw);

  // flash attention -> bf16 [2048][4096]
  attn_k<<<1024, 256, 0, stream>>>(qkv, ao);

  // output projection: BM=128, grid 256 (16M x 16N, XCD chunks 8Mx4N),
  // full-K, f32 -> d_out
  gemm8p<64, true, false><<<256, 512, 0, stream>>>(
      ao, wbo, d_out, 4096, 64, 4096, 8, 4, 4, 256, nullptr, nullptr);
}